// Round 1
// baseline (701.850 us; speedup 1.0000x reference)
//
#include <hip/hip_runtime.h>
#include <math.h>

#define CLS 1000
#define NB 10
#define HIST (CLS * NB)

// Zero the global accumulators each call (graph-capture-safe).
__global__ void ece_init_kernel(unsigned* cnt_g, float* conf_g, unsigned* acc_g) {
    int i = blockIdx.x * blockDim.x + threadIdx.x;
    if (i < HIST) {
        cnt_g[i]  = 0u;
        conf_g[i] = 0.0f;
        acc_g[i]  = 0u;
    }
}

// Fused softmax + (class,bin) histogram. One wave (64 lanes) per row.
// LDS histogram is [bin][class] so address low bits = class = lane -> conflict-free.
__global__ __launch_bounds__(256) void ece_hist_kernel(
    const float* __restrict__ logits, const int* __restrict__ labels,
    unsigned* __restrict__ cnt_g, float* __restrict__ conf_g,
    unsigned* __restrict__ acc_g, int N)
{
    __shared__ unsigned cnt_s[HIST];   // 40 KB
    __shared__ float    conf_s[HIST];  // 40 KB
    for (int i = threadIdx.x; i < HIST; i += blockDim.x) {
        cnt_s[i]  = 0u;
        conf_s[i] = 0.0f;
    }
    __syncthreads();

    const int lane  = threadIdx.x & 63;
    const int wib   = threadIdx.x >> 6;
    const int wpb   = blockDim.x >> 6;
    const int gwave = blockIdx.x * wpb + wib;
    const int nwav  = gridDim.x * wpb;

    for (int row = gwave; row < N; row += nwav) {
        const float* rp = logits + (size_t)row * CLS;
        float v[16];
        #pragma unroll
        for (int j = 0; j < 16; ++j) {
            int c = lane + 64 * j;
            v[j] = (c < CLS) ? rp[c] : -INFINITY;
        }
        // wave-wide max
        float m = v[0];
        #pragma unroll
        for (int j = 1; j < 16; ++j) m = fmaxf(m, v[j]);
        #pragma unroll
        for (int off = 32; off; off >>= 1) m = fmaxf(m, __shfl_xor(m, off));
        // exp + wave-wide sum (exp(-inf)=0 handles the tail lanes)
        float s = 0.0f;
        #pragma unroll
        for (int j = 0; j < 16; ++j) {
            float e = expf(v[j] - m);
            v[j] = e;
            s += e;
        }
        #pragma unroll
        for (int off = 32; off; off >>= 1) s += __shfl_xor(s, off);
        const float inv = 1.0f / s;
        const int lab = labels[row];

        #pragma unroll
        for (int j = 0; j < 16; ++j) {
            int c = lane + 64 * j;
            if (c < CLS) {
                float p = v[j] * inv;
                if (p > 0.0f) {
                    int bin = (int)ceilf(p * (float)NB) - 1;
                    bin = bin < 0 ? 0 : (bin > NB - 1 ? NB - 1 : bin);
                    int idx = bin * CLS + c;
                    atomicAdd(&cnt_s[idx], 1u);
                    atomicAdd(&conf_s[idx], p);
                    if (c == lab) atomicAdd(&acc_g[idx], 1u);  // rare: once per row
                }
            }
        }
    }

    __syncthreads();
    // merge block-private histogram into global; skip empty slots
    for (int i = threadIdx.x; i < HIST; i += blockDim.x) {
        unsigned u = cnt_s[i];
        if (u) {
            atomicAdd(&cnt_g[i], u);
            atomicAdd(&conf_g[i], conf_s[i]);
        }
    }
}

// final = sum_{c,b: cnt>0} |conf - acc| / (N * C)
__global__ void ece_final_kernel(const unsigned* __restrict__ cnt_g,
                                 const float* __restrict__ conf_g,
                                 const unsigned* __restrict__ acc_g,
                                 float* __restrict__ out, int N)
{
    __shared__ double wsum[16];
    double s = 0.0;
    for (int i = threadIdx.x; i < HIST; i += blockDim.x) {
        if (cnt_g[i] > 0u) {
            s += fabs((double)conf_g[i] - (double)acc_g[i]);
        }
    }
    #pragma unroll
    for (int off = 32; off; off >>= 1) s += __shfl_xor(s, off);
    int lane = threadIdx.x & 63, w = threadIdx.x >> 6;
    if (lane == 0) wsum[w] = s;
    __syncthreads();
    if (threadIdx.x == 0) {
        double t = 0.0;
        int nw = blockDim.x >> 6;
        for (int i = 0; i < nw; ++i) t += wsum[i];
        out[0] = (float)(t / ((double)N * (double)CLS));
    }
}

extern "C" void kernel_launch(void* const* d_in, const int* in_sizes, int n_in,
                              void* d_out, int out_size, void* d_ws, size_t ws_size,
                              hipStream_t stream) {
    const float* logits = (const float*)d_in[0];
    const int*   labels = (const int*)d_in[1];
    const int N = in_sizes[1];

    unsigned* cnt_g  = (unsigned*)d_ws;
    float*    conf_g = (float*)((char*)d_ws + HIST * sizeof(unsigned));
    unsigned* acc_g  = (unsigned*)((char*)d_ws + 2u * HIST * sizeof(unsigned));
    float*    out    = (float*)d_out;

    ece_init_kernel<<<(HIST + 255) / 256, 256, 0, stream>>>(cnt_g, conf_g, acc_g);
    // 2 blocks/CU (80 KB LDS each) x 256 CUs
    ece_hist_kernel<<<512, 256, 0, stream>>>(logits, labels, cnt_g, conf_g, acc_g, N);
    ece_final_kernel<<<1, 1024, 0, stream>>>(cnt_g, conf_g, acc_g, out, N);
}

// Round 2
// 373.663 us; speedup vs baseline: 1.8783x; 1.8783x over previous
//
#include <hip/hip_runtime.h>
#include <math.h>

#define CLS 1000
#define NB 10
#define HIST (CLS * NB)

// Zero global accumulators each call (graph-capture-safe, deterministic).
__global__ void ece_init_kernel(float* conf_g, unsigned* acc_g) {
    int i = blockIdx.x * blockDim.x + threadIdx.x;
    if (i < HIST) {
        conf_g[i] = 0.0f;
        acc_g[i]  = 0u;
    }
}

// Fused softmax + (class,bin) confidence histogram.
// One wave per 2 rows per iteration (ILP), software prefetch of next pair.
// LDS: conf only (cnt is algebraically unnecessary: cnt==0 => conf==acc==0).
// c = lane + 64*j  => LDS atomic addresses are stride-1 in lane => conflict-free.
__global__ __launch_bounds__(256, 4) void ece_hist_kernel(
    const float* __restrict__ logits, const int* __restrict__ labels,
    float* __restrict__ conf_g, unsigned* __restrict__ acc_g, int N)
{
    __shared__ float conf_s[HIST];  // 40 KB -> 4 blocks/CU
    for (int i = threadIdx.x; i < HIST; i += blockDim.x) conf_s[i] = 0.0f;
    __syncthreads();

    const int lane = threadIdx.x & 63;
    const int wib  = threadIdx.x >> 6;
    const int wpb  = blockDim.x >> 6;
    const int gw   = blockIdx.x * wpb + wib;
    const int nw   = gridDim.x * wpb;

    const int npair = N >> 1;

    float a0[16], a1[16];   // current pair
    int p = gw;
    if (p < npair) {
        // preload first pair
        {
            const float* r0p = logits + (size_t)(2 * p) * CLS;
            const float* r1p = r0p + CLS;
            #pragma unroll
            for (int j = 0; j < 16; ++j) {
                int c = lane + 64 * j;
                bool ok = c < CLS;
                int cc = ok ? c : 0;
                float x0 = r0p[cc], x1 = r1p[cc];
                a0[j] = ok ? x0 : -INFINITY;
                a1[j] = ok ? x1 : -INFINITY;
            }
        }
        for (; p < npair; p += nw) {
            const int pn  = p + nw;
            const int pnc = (pn < npair) ? pn : p;
            // issue next pair's loads early (hide HBM latency under compute)
            float b0[16], b1[16];
            {
                const float* r0p = logits + (size_t)(2 * pnc) * CLS;
                const float* r1p = r0p + CLS;
                #pragma unroll
                for (int j = 0; j < 16; ++j) {
                    int c = lane + 64 * j;
                    bool ok = c < CLS;
                    int cc = ok ? c : 0;
                    float x0 = r0p[cc], x1 = r1p[cc];
                    b0[j] = ok ? x0 : -INFINITY;
                    b1[j] = ok ? x1 : -INFINITY;
                }
            }

            // wave-wide max (both rows interleaved)
            float m0 = a0[0], m1 = a1[0];
            #pragma unroll
            for (int j = 1; j < 16; ++j) { m0 = fmaxf(m0, a0[j]); m1 = fmaxf(m1, a1[j]); }
            #pragma unroll
            for (int off = 32; off; off >>= 1) {
                m0 = fmaxf(m0, __shfl_xor(m0, off));
                m1 = fmaxf(m1, __shfl_xor(m1, off));
            }
            // exp + wave-wide sum
            float s0 = 0.0f, s1 = 0.0f;
            #pragma unroll
            for (int j = 0; j < 16; ++j) {
                float e0 = __expf(a0[j] - m0);
                float e1 = __expf(a1[j] - m1);
                a0[j] = e0; a1[j] = e1;
                s0 += e0; s1 += e1;
            }
            #pragma unroll
            for (int off = 32; off; off >>= 1) {
                s0 += __shfl_xor(s0, off);
                s1 += __shfl_xor(s1, off);
            }
            const float i0 = 1.0f / s0;
            const float i1 = 1.0f / s1;
            const int lab0 = labels[2 * p];
            const int lab1 = labels[2 * p + 1];

            #pragma unroll
            for (int j = 0; j < 16; ++j) {
                int c = lane + 64 * j;
                if (c < CLS) {
                    float q0 = a0[j] * i0;
                    float q1 = a1[j] * i1;
                    bool g0 = q0 > 0.0f, g1 = q1 > 0.0f;
                    int bb0 = (int)ceilf(q0 * (float)NB) - 1;
                    int bb1 = (int)ceilf(q1 * (float)NB) - 1;
                    bb0 = bb0 < 0 ? 0 : (bb0 > NB - 1 ? NB - 1 : bb0);
                    bb1 = bb1 < 0 ? 0 : (bb1 > NB - 1 ? NB - 1 : bb1);
                    int id0 = bb0 * CLS + c;
                    int id1 = bb1 * CLS + c;
                    if (g0 && g1 && id0 == id1) {
                        atomicAdd(&conf_s[id0], q0 + q1);
                    } else {
                        if (g0) atomicAdd(&conf_s[id0], q0);
                        if (g1) atomicAdd(&conf_s[id1], q1);
                    }
                    if (g0 && c == lab0) atomicAdd(&acc_g[id0], 1u);
                    if (g1 && c == lab1) atomicAdd(&acc_g[id1], 1u);
                }
            }

            // rotate buffers (b -> a)
            #pragma unroll
            for (int j = 0; j < 16; ++j) { a0[j] = b0[j]; a1[j] = b1[j]; }
        }
    }

    // odd-N tail row (not hit for N=131072, kept for correctness)
    if ((N & 1) && gw == 0) {
        int row = N - 1;
        const float* rp = logits + (size_t)row * CLS;
        float v[16];
        #pragma unroll
        for (int j = 0; j < 16; ++j) {
            int c = lane + 64 * j;
            v[j] = (c < CLS) ? rp[c] : -INFINITY;
        }
        float m = v[0];
        #pragma unroll
        for (int j = 1; j < 16; ++j) m = fmaxf(m, v[j]);
        #pragma unroll
        for (int off = 32; off; off >>= 1) m = fmaxf(m, __shfl_xor(m, off));
        float s = 0.0f;
        #pragma unroll
        for (int j = 0; j < 16; ++j) { v[j] = __expf(v[j] - m); s += v[j]; }
        #pragma unroll
        for (int off = 32; off; off >>= 1) s += __shfl_xor(s, off);
        float inv = 1.0f / s;
        int lab = labels[row];
        #pragma unroll
        for (int j = 0; j < 16; ++j) {
            int c = lane + 64 * j;
            if (c < CLS) {
                float q = v[j] * inv;
                if (q > 0.0f) {
                    int b = (int)ceilf(q * (float)NB) - 1;
                    b = b < 0 ? 0 : (b > NB - 1 ? NB - 1 : b);
                    int idx = b * CLS + c;
                    atomicAdd(&conf_g[idx], q);
                    if (c == lab) atomicAdd(&acc_g[idx], 1u);
                }
            }
        }
    }

    __syncthreads();
    // merge block-private conf into global; skip empty slots
    for (int i = threadIdx.x; i < HIST; i += blockDim.x) {
        float v = conf_s[i];
        if (v != 0.0f) atomicAdd(&conf_g[i], v);
    }
}

// final = sum_i |conf_i - acc_i| / (N * C)   (cnt==0 slots contribute 0)
__global__ void ece_final_kernel(const float* __restrict__ conf_g,
                                 const unsigned* __restrict__ acc_g,
                                 float* __restrict__ out, int N)
{
    __shared__ double wsum[16];
    double s = 0.0;
    for (int i = threadIdx.x; i < HIST; i += blockDim.x) {
        s += fabs((double)conf_g[i] - (double)acc_g[i]);
    }
    #pragma unroll
    for (int off = 32; off; off >>= 1) s += __shfl_xor(s, off);
    int lane = threadIdx.x & 63, w = threadIdx.x >> 6;
    if (lane == 0) wsum[w] = s;
    __syncthreads();
    if (threadIdx.x == 0) {
        double t = 0.0;
        int nwv = blockDim.x >> 6;
        for (int i = 0; i < nwv; ++i) t += wsum[i];
        out[0] = (float)(t / ((double)N * (double)CLS));
    }
}

extern "C" void kernel_launch(void* const* d_in, const int* in_sizes, int n_in,
                              void* d_out, int out_size, void* d_ws, size_t ws_size,
                              hipStream_t stream) {
    const float* logits = (const float*)d_in[0];
    const int*   labels = (const int*)d_in[1];
    const int N = in_sizes[1];

    float*    conf_g = (float*)d_ws;
    unsigned* acc_g  = (unsigned*)((char*)d_ws + HIST * sizeof(float));
    float*    out    = (float*)d_out;

    ece_init_kernel<<<(HIST + 255) / 256, 256, 0, stream>>>(conf_g, acc_g);
    // 4 blocks/CU (40 KB LDS each) x 256 CUs
    ece_hist_kernel<<<1024, 256, 0, stream>>>(logits, labels, conf_g, acc_g, N);
    ece_final_kernel<<<1, 1024, 0, stream>>>(conf_g, acc_g, out, N);
}